// Round 2
// baseline (589.659 us; speedup 1.0000x reference)
//
#include <hip/hip_runtime.h>
#include <hip/hip_bf16.h>

#define DIM       4096
#define NHEADS    32
#define NKV       8
#define HD        128
#define NREP      4
#define CACHELEN  2080
#define QKVN      6144   /* 4096 q + 1024 k + 1024 v */
#define BSZ       32
#define SP0       2048
#define SP1       1024
#define KCHUNK    256
#define SPLITROWS 128    /* uniform rows per flash-decode split */
#define MAXSPL    16     /* sp0/128 */
#define PSTRIDE   132    /* per-(b,g,s,h) partial: 128 acc + m + l, padded */

typedef unsigned short u16;
typedef unsigned int   u32;
typedef __bf16 bf16x8 __attribute__((ext_vector_type(8)));
typedef float  f32x4  __attribute__((ext_vector_type(4)));

#define LD8(dst, p) do { \
    *(float4*)(dst)       = *(const float4*)(p); \
    *(float4*)((dst) + 4) = *(const float4*)((p) + 4); } while (0)

static __device__ __forceinline__ bf16x8 pack8(float4 lo, float4 hi) {
    bf16x8 r;
    r[0] = (__bf16)lo.x; r[1] = (__bf16)lo.y; r[2] = (__bf16)lo.z; r[3] = (__bf16)lo.w;
    r[4] = (__bf16)hi.x; r[5] = (__bf16)hi.y; r[6] = (__bf16)hi.z; r[7] = (__bf16)hi.w;
    return r;
}

// ---------------------------------------------------------------------------
// K1: QKV projection. out[m][n] = sum_k x[m][k] * W[n][k], W in {wq,wk,wv}.
// ---------------------------------------------------------------------------
__global__ __launch_bounds__(256) void qkv_gemm(
    const float* __restrict__ x, const float* __restrict__ wq,
    const float* __restrict__ wk, const float* __restrict__ wv,
    float* __restrict__ qkv_acc)
{
    const int lane = threadIdx.x & 63;
    const int w    = threadIdx.x >> 6;
    const int n0   = (blockIdx.x * 4 + w) * 16;
    const float* W; int nr;
    if (n0 < 4096)      { W = wq; nr = n0; }
    else if (n0 < 5120) { W = wk; nr = n0 - 4096; }
    else                { W = wv; nr = n0 - 5120; }
    const int c16  = lane & 15;
    const int quad = lane >> 4;
    const int k0   = blockIdx.y * KCHUNK;
    const float* ap0 = x + (size_t)c16 * DIM + k0 + quad * 8;
    const float* ap1 = ap0 + 16 * DIM;
    const float* bp  = W + (size_t)(nr + c16) * DIM + k0 + quad * 8;
    f32x4 acc0 = {0.f,0.f,0.f,0.f}, acc1 = {0.f,0.f,0.f,0.f};
#pragma unroll 4
    for (int kk = 0; kk < KCHUNK; kk += 32) {
        bf16x8 a0 = pack8(*(const float4*)(ap0 + kk), *(const float4*)(ap0 + kk + 4));
        bf16x8 a1 = pack8(*(const float4*)(ap1 + kk), *(const float4*)(ap1 + kk + 4));
        bf16x8 b  = pack8(*(const float4*)(bp  + kk), *(const float4*)(bp  + kk + 4));
        acc0 = __builtin_amdgcn_mfma_f32_16x16x32_bf16(a0, b, acc0, 0, 0, 0);
        acc1 = __builtin_amdgcn_mfma_f32_16x16x32_bf16(a1, b, acc1, 0, 0, 0);
    }
#pragma unroll
    for (int r = 0; r < 4; ++r) {
        int m = quad * 4 + r;
        atomicAdd(&qkv_acc[(size_t)m * QKVN + n0 + c16], acc0[r]);
        atomicAdd(&qkv_acc[(size_t)(m + 16) * QKVN + n0 + c16], acc1[r]);
    }
}

// ---------------------------------------------------------------------------
// K2: flash-decode attention with uniform 128-row splits and a depth-2
// register software pipeline. grid.x = 16*8*16 + 16*8*8 = 3072 blocks,
// all equal work (4 iters of 32 rows).
// Lane partition: ch = lane&15 covers dims [ch*8, ch*8+8); quad = lane>>4
// selects the row within a 4-row coalesced wave load.
// ---------------------------------------------------------------------------
__global__ __launch_bounds__(256) void attn_decode_split(
    const float* __restrict__ qkv,
    const float* __restrict__ ck0, const float* __restrict__ cv0,
    const float* __restrict__ ck1, const float* __restrict__ cv1,
    const float* __restrict__ fcos, const float* __restrict__ fsin,
    float* __restrict__ part)
{
    const int tid  = threadIdx.x;
    const int lane = tid & 63;
    const int w    = tid >> 6;
    const int quad = lane >> 4;
    const int ch   = lane & 15;
    const int db   = ch * 8;

    int b, g, s, sp;
    const float *CK, *CV;
    if ((int)blockIdx.x < 2048) {
        int bid = blockIdx.x;
        b = bid >> 7; g = (bid >> 4) & 7; s = bid & 15; sp = SP0;
        size_t off = (size_t)b * CACHELEN * NKV * HD;
        CK = ck0 + off; CV = cv0 + off;
    } else {
        int bid = blockIdx.x - 2048;
        b = 16 + (bid >> 6); g = (bid >> 3) & 7; s = bid & 7; sp = SP1;
        size_t off = (size_t)(b - 16) * CACHELEN * NKV * HD;
        CK = ck1 + off; CV = cv1 + off;
    }

    // RoPE cos/sin for this lane's 4 pairs at position sp
    float cs[4], sn[4];
#pragma unroll
    for (int i = 0; i < 4; ++i) {
        int fi = sp * (HD / 2) + ch * 4 + i;
        cs[i] = fcos[fi];
        sn[i] = fsin[fi];
    }
    const float rs = 0.08838834764831845f; // 1/sqrt(128)

    // q for the 4 heads of this group: rope + fold in 1/sqrt(d)
    float qv[4][8];
#pragma unroll
    for (int h = 0; h < 4; ++h) {
        const float* qp = qkv + (size_t)b * QKVN + (g * 4 + h) * HD + db;
        float t[8];
#pragma unroll
        for (int j = 0; j < 8; ++j) t[j] = qp[j];
#pragma unroll
        for (int i = 0; i < 4; ++i) {
            float e = t[2 * i], o = t[2 * i + 1];
            qv[h][2 * i]     = (e * cs[i] - o * sn[i]) * rs;
            qv[h][2 * i + 1] = (e * sn[i] + o * cs[i]) * rs;
        }
    }

    float m_[4] = {-INFINITY, -INFINITY, -INFINITY, -INFINITY};
    float l_[4] = {0.f, 0.f, 0.f, 0.f};
    float acc[4][8];
#pragma unroll
    for (int h = 0; h < 4; ++h)
#pragma unroll
        for (int j = 0; j < 8; ++j) acc[h][j] = 0.f;

    const size_t rstride = NKV * HD; // 1024 floats per cache row
    const float* kbase = CK + g * HD + db;
    const float* vbase = CV + g * HD + db;

    // merged 2-row softmax step: one rescale per head covering both rows
    auto process2 = [&](const float* k0, const float* v0,
                        const float* k1, const float* v1) {
        float d[8];
#pragma unroll
        for (int i = 0; i < 8; ++i) d[i] = 0.f;
#pragma unroll
        for (int j = 0; j < 8; ++j) {
#pragma unroll
            for (int h = 0; h < 4; ++h) {
                d[h]     = fmaf(qv[h][j], k0[j], d[h]);
                d[4 + h] = fmaf(qv[h][j], k1[j], d[4 + h]);
            }
        }
#pragma unroll
        for (int off = 1; off < 16; off <<= 1) {
#pragma unroll
            for (int i = 0; i < 8; ++i) d[i] += __shfl_xor(d[i], off);
        }
#pragma unroll
        for (int h = 0; h < 4; ++h) {
            float mn = fmaxf(fmaxf(m_[h], d[h]), d[4 + h]);
            float sl = __expf(m_[h] - mn);
            float p0 = __expf(d[h] - mn);
            float p1 = __expf(d[4 + h] - mn);
            l_[h] = l_[h] * sl + p0 + p1;
#pragma unroll
            for (int j = 0; j < 8; ++j)
                acc[h][j] = fmaf(p1, v1[j], fmaf(p0, v0[j], acc[h][j] * sl));
            m_[h] = mn;
        }
    };

    // depth-2 software pipeline over 4 iterations of 32 rows
    {
        const int r0 = s * SPLITROWS + w * 8 + quad;
        const float* kp = kbase + (size_t)r0 * rstride;
        const float* vp = vbase + (size_t)r0 * rstride;
        float K0[8], V0[8], K1[8], V1[8];
        float nK0[8], nV0[8], nK1[8], nV1[8];
        LD8(K0, kp);
        LD8(K1, kp + 4 * rstride);
        LD8(V0, vp);
        LD8(V1, vp + 4 * rstride);
#pragma unroll
        for (int it = 0; it < 4; ++it) {
            if (it < 3) {
                const float* kq = kp + (size_t)(it + 1) * 32 * rstride;
                const float* vq = vp + (size_t)(it + 1) * 32 * rstride;
                LD8(nK0, kq);
                LD8(nK1, kq + 4 * rstride);
                LD8(nV0, vq);
                LD8(nV1, vq + 4 * rstride);
            }
            process2(K0, V0, K1, V1);
            if (it < 3) {
#pragma unroll
                for (int j = 0; j < 8; ++j) {
                    K0[j] = nK0[j]; K1[j] = nK1[j];
                    V0[j] = nV0[j]; V1[j] = nV1[j];
                }
            }
        }
    }

    // new token (position sp): handled once, by split 0
    if (s == 0) {
        float kn[8], vn[8];
        const float* kp = qkv + (size_t)b * QKVN + 4096 + g * HD + db;
        const float* vp = qkv + (size_t)b * QKVN + 5120 + g * HD + db;
        float t[8];
#pragma unroll
        for (int j = 0; j < 8; ++j) t[j] = kp[j];
#pragma unroll
        for (int i = 0; i < 4; ++i) {
            float e = t[2 * i], o = t[2 * i + 1];
            kn[2 * i]     = e * cs[i] - o * sn[i];
            kn[2 * i + 1] = e * sn[i] + o * cs[i];
        }
#pragma unroll
        for (int j = 0; j < 8; ++j) vn[j] = vp[j];

        float d0 = 0.f, d1 = 0.f, d2 = 0.f, d3 = 0.f;
#pragma unroll
        for (int j = 0; j < 8; ++j) {
            d0 = fmaf(qv[0][j], kn[j], d0);
            d1 = fmaf(qv[1][j], kn[j], d1);
            d2 = fmaf(qv[2][j], kn[j], d2);
            d3 = fmaf(qv[3][j], kn[j], d3);
        }
#pragma unroll
        for (int off = 1; off < 16; off <<= 1) {
            d0 += __shfl_xor(d0, off);
            d1 += __shfl_xor(d1, off);
            d2 += __shfl_xor(d2, off);
            d3 += __shfl_xor(d3, off);
        }
        if (w == 0 && quad == 0) {
            float sc[4] = {d0, d1, d2, d3};
#pragma unroll
            for (int h = 0; h < 4; ++h) {
                float mn = fmaxf(m_[h], sc[h]);
                float sl = __expf(m_[h] - mn);
                float p  = __expf(sc[h] - mn);
                l_[h] = l_[h] * sl + p;
#pragma unroll
                for (int j = 0; j < 8; ++j)
                    acc[h][j] = fmaf(acc[h][j], sl, p * vn[j]);
                m_[h] = mn;
            }
        }
    }

    // merge the 4 quads within each wave (lanes l, l^16, l^32 share ch)
#pragma unroll
    for (int off = 16; off <= 32; off <<= 1) {
#pragma unroll
        for (int h = 0; h < 4; ++h) {
            float mo = __shfl_xor(m_[h], off);
            float lo = __shfl_xor(l_[h], off);
            float ao[8];
#pragma unroll
            for (int j = 0; j < 8; ++j) ao[j] = __shfl_xor(acc[h][j], off);
            float mn = fmaxf(m_[h], mo);
            float s1 = __expf(m_[h] - mn);
            float s2 = __expf(mo - mn);
            l_[h] = l_[h] * s1 + lo * s2;
#pragma unroll
            for (int j = 0; j < 8; ++j) acc[h][j] = acc[h][j] * s1 + ao[j] * s2;
            m_[h] = mn;
        }
    }

    // cross-wave merge via LDS
    __shared__ float ls_m[4][4][16];
    __shared__ float ls_l[4][4][16];
    __shared__ float ls_a[4][4][16][8];
    if (quad == 0) {
#pragma unroll
        for (int h = 0; h < 4; ++h) {
            ls_m[w][h][ch] = m_[h];
            ls_l[w][h][ch] = l_[h];
#pragma unroll
            for (int j = 0; j < 8; ++j) ls_a[w][h][ch][j] = acc[h][j];
        }
    }
    __syncthreads();
    if (tid < 64) {
        int h = tid >> 4, c = tid & 15;
        float mm = -INFINITY, ll = 0.f, ac[8] = {0.f,0.f,0.f,0.f,0.f,0.f,0.f,0.f};
#pragma unroll
        for (int w2 = 0; w2 < 4; ++w2) {
            float m2 = ls_m[w2][h][c], l2 = ls_l[w2][h][c];
            float mn = fmaxf(mm, m2);
            float s1 = __expf(mm - mn), s2 = __expf(m2 - mn);
            ll = ll * s1 + l2 * s2;
#pragma unroll
            for (int j = 0; j < 8; ++j) ac[j] = ac[j] * s1 + ls_a[w2][h][c][j] * s2;
            mm = mn;
        }
        // write unnormalized partial (fixed MAXSPL slots per (b,g))
        int bg = b * 8 + g;
        float* pp = part + ((((size_t)bg * MAXSPL + s) * 4 + h) * PSTRIDE);
        float4 o0, o1;
        o0.x = ac[0]; o0.y = ac[1]; o0.z = ac[2]; o0.w = ac[3];
        o1.x = ac[4]; o1.y = ac[5]; o1.z = ac[6]; o1.w = ac[7];
        *(float4*)(pp + c * 8)     = o0;
        *(float4*)(pp + c * 8 + 4) = o1;
        if (c == 0) { pp[128] = mm; pp[129] = ll; }
    }
}

// ---------------------------------------------------------------------------
// K2b: merge the per-(b,g) partials and write normalized attn.
// One wave per (b,g); lane: h = lane>>4, c = lane&15.
// ---------------------------------------------------------------------------
__global__ __launch_bounds__(64) void attn_reduce(
    const float* __restrict__ part, float* __restrict__ attn)
{
    const int lane = threadIdx.x;
    const int h = lane >> 4, c = lane & 15;
    const int bg = blockIdx.x;              // b*8 + g
    const int b = bg >> 3, g = bg & 7;
    const int nspl = (b < 16) ? (SP0 / SPLITROWS) : (SP1 / SPLITROWS);
    const float* pb = part + (size_t)bg * MAXSPL * 4 * PSTRIDE;

    float mm = -INFINITY, ll = 0.f, ac[8] = {0.f,0.f,0.f,0.f,0.f,0.f,0.f,0.f};
    for (int s = 0; s < nspl; ++s) {
        const float* pp = pb + ((size_t)s * 4 + h) * PSTRIDE;
        float m2 = pp[128], l2 = pp[129];
        float4 a0 = *(const float4*)(pp + c * 8);
        float4 a1 = *(const float4*)(pp + c * 8 + 4);
        float a2[8] = {a0.x, a0.y, a0.z, a0.w, a1.x, a1.y, a1.z, a1.w};
        float mn = fmaxf(mm, m2);
        float s1 = __expf(mm - mn), s2 = __expf(m2 - mn);
        ll = ll * s1 + l2 * s2;
#pragma unroll
        for (int j = 0; j < 8; ++j) ac[j] = ac[j] * s1 + a2[j] * s2;
        mm = mn;
    }
    float inv = 1.f / ll;
    float* op = attn + (size_t)b * DIM + (g * 4 + h) * HD + c * 8;
    float4 o0, o1;
    o0.x = ac[0] * inv; o0.y = ac[1] * inv; o0.z = ac[2] * inv; o0.w = ac[3] * inv;
    o1.x = ac[4] * inv; o1.y = ac[5] * inv; o1.z = ac[6] * inv; o1.w = ac[7] * inv;
    *(float4*)op       = o0;
    *(float4*)(op + 4) = o1;
}

// ---------------------------------------------------------------------------
// K3: output projection. out[m][n] = sum_k attn[m][k] * wo[n][k]
// ---------------------------------------------------------------------------
__global__ __launch_bounds__(256) void out_gemm(
    const float* __restrict__ A, const float* __restrict__ wo,
    float* __restrict__ out)
{
    const int lane = threadIdx.x & 63;
    const int w    = threadIdx.x >> 6;
    const int n0   = (blockIdx.x * 4 + w) * 16;
    const int c16  = lane & 15;
    const int quad = lane >> 4;
    const int k0   = blockIdx.y * KCHUNK;
    const float* ap0 = A + (size_t)c16 * DIM + k0 + quad * 8;
    const float* ap1 = ap0 + 16 * DIM;
    const float* bp  = wo + (size_t)(n0 + c16) * DIM + k0 + quad * 8;
    f32x4 acc0 = {0.f,0.f,0.f,0.f}, acc1 = {0.f,0.f,0.f,0.f};
#pragma unroll 4
    for (int kk = 0; kk < KCHUNK; kk += 32) {
        bf16x8 a0 = pack8(*(const float4*)(ap0 + kk), *(const float4*)(ap0 + kk + 4));
        bf16x8 a1 = pack8(*(const float4*)(ap1 + kk), *(const float4*)(ap1 + kk + 4));
        bf16x8 b  = pack8(*(const float4*)(bp  + kk), *(const float4*)(bp  + kk + 4));
        acc0 = __builtin_amdgcn_mfma_f32_16x16x32_bf16(a0, b, acc0, 0, 0, 0);
        acc1 = __builtin_amdgcn_mfma_f32_16x16x32_bf16(a1, b, acc1, 0, 0, 0);
    }
#pragma unroll
    for (int r = 0; r < 4; ++r) {
        int m = quad * 4 + r;
        atomicAdd(&out[(size_t)m * DIM + n0 + c16], acc0[r]);
        atomicAdd(&out[(size_t)(m + 16) * DIM + n0 + c16], acc1[r]);
    }
}

extern "C" void kernel_launch(void* const* d_in, const int* in_sizes, int n_in,
                              void* d_out, int out_size, void* d_ws, size_t ws_size,
                              hipStream_t stream)
{
    const float* x   = (const float*)d_in[0];
    const float* wq  = (const float*)d_in[1];
    const float* wk  = (const float*)d_in[2];
    const float* wv  = (const float*)d_in[3];
    const float* wo  = (const float*)d_in[4];
    const float* ck0 = (const float*)d_in[5];
    const float* cv0 = (const float*)d_in[6];
    const float* ck1 = (const float*)d_in[7];
    const float* cv1 = (const float*)d_in[8];
    const float* fc  = (const float*)d_in[9];
    const float* fs  = (const float*)d_in[10];

    float* qkv_acc = (float*)d_ws;                         // 32*6144 f32
    float* attn    = qkv_acc + BSZ * QKVN;                 // 32*4096 f32
    float* part    = attn + BSZ * DIM;                     // 256*16*4*132 f32
    float* out     = (float*)d_out;                        // 32*4096 f32

    hipMemsetAsync(qkv_acc, 0, (size_t)(BSZ * QKVN) * sizeof(float), stream);
    hipMemsetAsync(out, 0, (size_t)(BSZ * DIM) * sizeof(float), stream);

    qkv_gemm<<<dim3(QKVN / 64, DIM / KCHUNK), 256, 0, stream>>>(x, wq, wk, wv, qkv_acc);
    attn_decode_split<<<dim3(2048 + 1024), 256, 0, stream>>>(qkv_acc, ck0, cv0, ck1, cv1, fc, fs, part);
    attn_reduce<<<dim3(BSZ * NKV), 64, 0, stream>>>(part, attn);
    out_gemm<<<dim3(DIM / 64, DIM / KCHUNK), 256, 0, stream>>>(attn, wo, out);
}

// Round 3
// 571.734 us; speedup vs baseline: 1.0314x; 1.0314x over previous
//
#include <hip/hip_runtime.h>
#include <hip/hip_bf16.h>

#define DIM       4096
#define NHEADS    32
#define NKV       8
#define HD        128
#define NREP      4
#define CACHELEN  2080
#define QKVN      6144   /* 4096 q + 1024 k + 1024 v */
#define BSZ       32
#define SP0       2048
#define SP1       1024
#define KCHUNK    512
#define NSPLK     8      /* GEMM k-splits */
#define SPLITROWS 256    /* rows per flash-decode split (2 batches of 128) */
#define MAXSPL    8      /* sp0/256 */
#define PSTRIDE   132    /* per-(b,g,s,h) partial: 128 acc + m + l, padded */

typedef unsigned short u16;
typedef unsigned int   u32;
typedef __bf16 bf16x8 __attribute__((ext_vector_type(8)));
typedef float  f32x4  __attribute__((ext_vector_type(4)));

#define LD8(dst, p) do { \
    *(float4*)(dst)       = *(const float4*)(p); \
    *(float4*)((dst) + 4) = *(const float4*)((p) + 4); } while (0)

static __device__ __forceinline__ bf16x8 pack8(float4 lo, float4 hi) {
    bf16x8 r;
    r[0] = (__bf16)lo.x; r[1] = (__bf16)lo.y; r[2] = (__bf16)lo.z; r[3] = (__bf16)lo.w;
    r[4] = (__bf16)hi.x; r[5] = (__bf16)hi.y; r[6] = (__bf16)hi.z; r[7] = (__bf16)hi.w;
    return r;
}

// ---------------------------------------------------------------------------
// K1: QKV projection. out[m][n] = sum_k x[m][k] * W[n][k], W in {wq,wk,wv}.
// Each k-split writes its own partial slice (no atomics).
// ---------------------------------------------------------------------------
__global__ __launch_bounds__(256) void qkv_gemm(
    const float* __restrict__ x, const float* __restrict__ wq,
    const float* __restrict__ wk, const float* __restrict__ wv,
    float* __restrict__ qkv_part)
{
    const int lane = threadIdx.x & 63;
    const int w    = threadIdx.x >> 6;
    const int n0   = (blockIdx.x * 4 + w) * 16;
    const float* W; int nr;
    if (n0 < 4096)      { W = wq; nr = n0; }
    else if (n0 < 5120) { W = wk; nr = n0 - 4096; }
    else                { W = wv; nr = n0 - 5120; }
    const int c16  = lane & 15;
    const int quad = lane >> 4;
    const int k0   = blockIdx.y * KCHUNK;
    const float* ap0 = x + (size_t)c16 * DIM + k0 + quad * 8;
    const float* ap1 = ap0 + 16 * DIM;
    const float* bp  = W + (size_t)(nr + c16) * DIM + k0 + quad * 8;
    f32x4 acc0 = {0.f,0.f,0.f,0.f}, acc1 = {0.f,0.f,0.f,0.f};
#pragma unroll 4
    for (int kk = 0; kk < KCHUNK; kk += 32) {
        bf16x8 a0 = pack8(*(const float4*)(ap0 + kk), *(const float4*)(ap0 + kk + 4));
        bf16x8 a1 = pack8(*(const float4*)(ap1 + kk), *(const float4*)(ap1 + kk + 4));
        bf16x8 b  = pack8(*(const float4*)(bp  + kk), *(const float4*)(bp  + kk + 4));
        acc0 = __builtin_amdgcn_mfma_f32_16x16x32_bf16(a0, b, acc0, 0, 0, 0);
        acc1 = __builtin_amdgcn_mfma_f32_16x16x32_bf16(a1, b, acc1, 0, 0, 0);
    }
    float* dst = qkv_part + (size_t)blockIdx.y * (BSZ * QKVN);
#pragma unroll
    for (int r = 0; r < 4; ++r) {
        int m = quad * 4 + r;
        dst[(size_t)m * QKVN + n0 + c16]        = acc0[r];
        dst[(size_t)(m + 16) * QKVN + n0 + c16] = acc1[r];
    }
}

// ---------------------------------------------------------------------------
// sum over NSPLK split slices (vectorized float4)
// ---------------------------------------------------------------------------
__global__ __launch_bounds__(256) void sum_splits(
    const float4* __restrict__ in, float4* __restrict__ out, int n4)
{
    int i = blockIdx.x * 256 + threadIdx.x;
    if (i >= n4) return;
    float4 s0 = in[i];
#pragma unroll
    for (int s = 1; s < NSPLK; ++s) {
        float4 t = in[(size_t)s * n4 + i];
        s0.x += t.x; s0.y += t.y; s0.z += t.z; s0.w += t.w;
    }
    out[i] = s0;
}

// ---------------------------------------------------------------------------
// K2: flash-decode attention, 256-row splits, scores-first batches of 128
// rows. Per batch: bulk-load 16 K rows/wave (16 dwordx4 per lane, all
// independent), all dots, one shfl-reduce pass, batch max, bulk-load V,
// ONE online-softmax update. Serial chain runs once per 128 rows instead
// of once per 2 rows.
// grid = 16*8*8 (sp0) + 16*8*4 (sp1) = 1536 blocks, uniform work.
// ---------------------------------------------------------------------------
__global__ __launch_bounds__(256) void attn_decode_split(
    const float* __restrict__ qkv,
    const float* __restrict__ ck0, const float* __restrict__ cv0,
    const float* __restrict__ ck1, const float* __restrict__ cv1,
    const float* __restrict__ fcos, const float* __restrict__ fsin,
    float* __restrict__ part)
{
    const int tid  = threadIdx.x;
    const int lane = tid & 63;
    const int w    = tid >> 6;
    const int quad = lane >> 4;
    const int ch   = lane & 15;
    const int db   = ch * 8;

    int b, g, s, sp;
    const float *CK, *CV;
    if ((int)blockIdx.x < 1024) {
        int bid = blockIdx.x;
        b = bid >> 6; g = (bid >> 3) & 7; s = bid & 7; sp = SP0;
        size_t off = (size_t)b * CACHELEN * NKV * HD;
        CK = ck0 + off; CV = cv0 + off;
    } else {
        int bid = blockIdx.x - 1024;
        b = 16 + (bid >> 5); g = (bid >> 2) & 7; s = bid & 3; sp = SP1;
        size_t off = (size_t)(b - 16) * CACHELEN * NKV * HD;
        CK = ck1 + off; CV = cv1 + off;
    }

    // RoPE cos/sin for this lane's 4 pairs at position sp
    float cs[4], sn[4];
#pragma unroll
    for (int i = 0; i < 4; ++i) {
        int fi = sp * (HD / 2) + ch * 4 + i;
        cs[i] = fcos[fi];
        sn[i] = fsin[fi];
    }
    const float rs = 0.08838834764831845f; // 1/sqrt(128)

    // q for the 4 heads of this group: rope + fold in 1/sqrt(d)
    float qv[4][8];
#pragma unroll
    for (int h = 0; h < 4; ++h) {
        const float* qp = qkv + (size_t)b * QKVN + (g * 4 + h) * HD + db;
        float t[8];
#pragma unroll
        for (int j = 0; j < 8; ++j) t[j] = qp[j];
#pragma unroll
        for (int i = 0; i < 4; ++i) {
            float e = t[2 * i], o = t[2 * i + 1];
            qv[h][2 * i]     = (e * cs[i] - o * sn[i]) * rs;
            qv[h][2 * i + 1] = (e * sn[i] + o * cs[i]) * rs;
        }
    }

    // new-token k (roped) and v — only needed by wave 0 of split 0
    const bool has_new = (s == 0) && (w == 0);
    float kn[8], vn[8];
    if (has_new) {
        const float* kp = qkv + (size_t)b * QKVN + 4096 + g * HD + db;
        const float* vp = qkv + (size_t)b * QKVN + 5120 + g * HD + db;
        float t[8];
#pragma unroll
        for (int j = 0; j < 8; ++j) t[j] = kp[j];
#pragma unroll
        for (int i = 0; i < 4; ++i) {
            float e = t[2 * i], o = t[2 * i + 1];
            kn[2 * i]     = e * cs[i] - o * sn[i];
            kn[2 * i + 1] = e * sn[i] + o * cs[i];
        }
#pragma unroll
        for (int j = 0; j < 8; ++j) vn[j] = vp[j];
    }

    float m_[4] = {-INFINITY, -INFINITY, -INFINITY, -INFINITY};
    float l_[4] = {0.f, 0.f, 0.f, 0.f};
    float acc[4][8];
#pragma unroll
    for (int h = 0; h < 4; ++h)
#pragma unroll
        for (int j = 0; j < 8; ++j) acc[h][j] = 0.f;

    const size_t rstride = NKV * HD; // 1024 floats per cache row
    const float* kp0 = CK + g * HD + db + (size_t)(s * SPLITROWS + w * 8 + quad) * rstride;
    const float* vp0 = CV + g * HD + db + (size_t)(s * SPLITROWS + w * 8 + quad) * rstride;

    // one 128-row batch: rows (it*32 + w*8 + quad + {0,4}) for it = 0..3
    auto do_batch = [&](const float* kpB, const float* vpB, bool fold_new) {
        float Ka[4][2][8];
#pragma unroll
        for (int it = 0; it < 4; ++it) {
            const float* kq = kpB + (size_t)(it * 32) * rstride;
            LD8(Ka[it][0], kq);
            LD8(Ka[it][1], kq + 4 * rstride);
        }
        float d[4][2][4];
#pragma unroll
        for (int it = 0; it < 4; ++it)
#pragma unroll
            for (int r = 0; r < 2; ++r)
#pragma unroll
                for (int h = 0; h < 4; ++h) d[it][r][h] = 0.f;
#pragma unroll
        for (int it = 0; it < 4; ++it)
#pragma unroll
            for (int j = 0; j < 8; ++j)
#pragma unroll
                for (int h = 0; h < 4; ++h) {
                    d[it][0][h] = fmaf(qv[h][j], Ka[it][0][j], d[it][0][h]);
                    d[it][1][h] = fmaf(qv[h][j], Ka[it][1][j], d[it][1][h]);
                }
        // reduce over the 16 ch lanes (32 independent chains)
#pragma unroll
        for (int off = 1; off < 16; off <<= 1)
#pragma unroll
            for (int it = 0; it < 4; ++it)
#pragma unroll
                for (int r = 0; r < 2; ++r)
#pragma unroll
                    for (int h = 0; h < 4; ++h)
                        d[it][r][h] += __shfl_xor(d[it][r][h], off);
        // batch max per head (wave-uniform after quad shfl)
        float bm[4];
#pragma unroll
        for (int h = 0; h < 4; ++h) {
            float a0 = fmaxf(fmaxf(d[0][0][h], d[0][1][h]), fmaxf(d[1][0][h], d[1][1][h]));
            float a1 = fmaxf(fmaxf(d[2][0][h], d[2][1][h]), fmaxf(d[3][0][h], d[3][1][h]));
            bm[h] = fmaxf(a0, a1);
        }
#pragma unroll
        for (int off = 16; off <= 32; off <<= 1)
#pragma unroll
            for (int h = 0; h < 4; ++h)
                bm[h] = fmaxf(bm[h], __shfl_xor(bm[h], off));
        // new-token score folded into this batch's max (wave-uniform)
        float dn[4] = {0.f, 0.f, 0.f, 0.f};
        if (fold_new) {
#pragma unroll
            for (int j = 0; j < 8; ++j)
#pragma unroll
                for (int h = 0; h < 4; ++h) dn[h] = fmaf(qv[h][j], kn[j], dn[h]);
#pragma unroll
            for (int off = 1; off < 16; off <<= 1)
#pragma unroll
                for (int h = 0; h < 4; ++h) dn[h] += __shfl_xor(dn[h], off);
#pragma unroll
            for (int h = 0; h < 4; ++h) bm[h] = fmaxf(bm[h], dn[h]);
        }
        // bulk V loads
        float Va[4][2][8];
#pragma unroll
        for (int it = 0; it < 4; ++it) {
            const float* vq = vpB + (size_t)(it * 32) * rstride;
            LD8(Va[it][0], vq);
            LD8(Va[it][1], vq + 4 * rstride);
        }
        // single online update for the whole batch
#pragma unroll
        for (int h = 0; h < 4; ++h) {
            float mn = fmaxf(m_[h], bm[h]);
            float sl = __expf(m_[h] - mn);
            float lb = 0.f;
#pragma unroll
            for (int it = 0; it < 4; ++it)
#pragma unroll
                for (int r = 0; r < 2; ++r) {
                    float p = __expf(d[it][r][h] - mn);
                    d[it][r][h] = p;
                    lb += p;
                }
            l_[h] = l_[h] * sl + lb;
#pragma unroll
            for (int j = 0; j < 8; ++j) {
                float a = acc[h][j] * sl;
#pragma unroll
                for (int it = 0; it < 4; ++it) {
                    a = fmaf(d[it][0][h], Va[it][0][j], a);
                    a = fmaf(d[it][1][h], Va[it][1][j], a);
                }
                acc[h][j] = a;
            }
            m_[h] = mn;
            if (fold_new && quad == 0) {
                float pn = __expf(dn[h] - mn);
                l_[h] += pn;
#pragma unroll
                for (int j = 0; j < 8; ++j) acc[h][j] = fmaf(pn, vn[j], acc[h][j]);
            }
        }
    };

    do_batch(kp0, vp0, false);
    do_batch(kp0 + 128 * rstride, vp0 + 128 * rstride, has_new);

    // quad merge: m_ is wave-uniform, so l_ and acc merge by pure sum
#pragma unroll
    for (int off = 16; off <= 32; off <<= 1) {
#pragma unroll
        for (int h = 0; h < 4; ++h) {
            l_[h] += __shfl_xor(l_[h], off);
#pragma unroll
            for (int j = 0; j < 8; ++j) acc[h][j] += __shfl_xor(acc[h][j], off);
        }
    }

    // cross-wave merge via LDS (rescale: waves have different m_)
    __shared__ float ls_m[4][4];
    __shared__ float ls_l[4][4];
    __shared__ float ls_a[4][4][16][8];
    if (lane == 0) {
#pragma unroll
        for (int h = 0; h < 4; ++h) { ls_m[w][h] = m_[h]; ls_l[w][h] = l_[h]; }
    }
    if (quad == 0) {
#pragma unroll
        for (int h = 0; h < 4; ++h)
#pragma unroll
            for (int j = 0; j < 8; ++j) ls_a[w][h][ch][j] = acc[h][j];
    }
    __syncthreads();
    if (tid < 64) {
        int h = tid >> 4, c = tid & 15;
        float mm = -INFINITY, ll = 0.f, ac[8] = {0.f,0.f,0.f,0.f,0.f,0.f,0.f,0.f};
#pragma unroll
        for (int w2 = 0; w2 < 4; ++w2) {
            float m2 = ls_m[w2][h], l2 = ls_l[w2][h];
            float mn = fmaxf(mm, m2);
            float s1 = __expf(mm - mn), s2 = __expf(m2 - mn);
            ll = ll * s1 + l2 * s2;
#pragma unroll
            for (int j = 0; j < 8; ++j) ac[j] = ac[j] * s1 + ls_a[w2][h][c][j] * s2;
            mm = mn;
        }
        int bg = b * 8 + g;
        float* pp = part + ((((size_t)bg * MAXSPL + s) * 4 + h) * PSTRIDE);
        float4 o0, o1;
        o0.x = ac[0]; o0.y = ac[1]; o0.z = ac[2]; o0.w = ac[3];
        o1.x = ac[4]; o1.y = ac[5]; o1.z = ac[6]; o1.w = ac[7];
        *(float4*)(pp + c * 8)     = o0;
        *(float4*)(pp + c * 8 + 4) = o1;
        if (c == 0) { pp[128] = mm; pp[129] = ll; }
    }
}

// ---------------------------------------------------------------------------
// K2b: merge the per-(b,g) split partials and write normalized attn.
// ---------------------------------------------------------------------------
__global__ __launch_bounds__(64) void attn_reduce(
    const float* __restrict__ part, float* __restrict__ attn)
{
    const int lane = threadIdx.x;
    const int h = lane >> 4, c = lane & 15;
    const int bg = blockIdx.x;              // b*8 + g
    const int b = bg >> 3, g = bg & 7;
    const int nspl = (b < 16) ? (SP0 / SPLITROWS) : (SP1 / SPLITROWS);
    const float* pb = part + (size_t)bg * MAXSPL * 4 * PSTRIDE;

    float mm = -INFINITY, ll = 0.f, ac[8] = {0.f,0.f,0.f,0.f,0.f,0.f,0.f,0.f};
    for (int s = 0; s < nspl; ++s) {
        const float* pp = pb + ((size_t)s * 4 + h) * PSTRIDE;
        float m2 = pp[128], l2 = pp[129];
        float4 a0 = *(const float4*)(pp + c * 8);
        float4 a1 = *(const float4*)(pp + c * 8 + 4);
        float a2[8] = {a0.x, a0.y, a0.z, a0.w, a1.x, a1.y, a1.z, a1.w};
        float mn = fmaxf(mm, m2);
        float s1 = __expf(mm - mn), s2 = __expf(m2 - mn);
        ll = ll * s1 + l2 * s2;
#pragma unroll
        for (int j = 0; j < 8; ++j) ac[j] = ac[j] * s1 + a2[j] * s2;
        mm = mn;
    }
    float inv = 1.f / ll;
    float* op = attn + (size_t)b * DIM + (g * 4 + h) * HD + c * 8;
    float4 o0, o1;
    o0.x = ac[0] * inv; o0.y = ac[1] * inv; o0.z = ac[2] * inv; o0.w = ac[3] * inv;
    o1.x = ac[4] * inv; o1.y = ac[5] * inv; o1.z = ac[6] * inv; o1.w = ac[7] * inv;
    *(float4*)op       = o0;
    *(float4*)(op + 4) = o1;
}

// ---------------------------------------------------------------------------
// K3: output projection partials (no atomics).
// ---------------------------------------------------------------------------
__global__ __launch_bounds__(256) void out_gemm(
    const float* __restrict__ A, const float* __restrict__ wo,
    float* __restrict__ out_part)
{
    const int lane = threadIdx.x & 63;
    const int w    = threadIdx.x >> 6;
    const int n0   = (blockIdx.x * 4 + w) * 16;
    const int c16  = lane & 15;
    const int quad = lane >> 4;
    const int k0   = blockIdx.y * KCHUNK;
    const float* ap0 = A + (size_t)c16 * DIM + k0 + quad * 8;
    const float* ap1 = ap0 + 16 * DIM;
    const float* bp  = wo + (size_t)(n0 + c16) * DIM + k0 + quad * 8;
    f32x4 acc0 = {0.f,0.f,0.f,0.f}, acc1 = {0.f,0.f,0.f,0.f};
#pragma unroll 4
    for (int kk = 0; kk < KCHUNK; kk += 32) {
        bf16x8 a0 = pack8(*(const float4*)(ap0 + kk), *(const float4*)(ap0 + kk + 4));
        bf16x8 a1 = pack8(*(const float4*)(ap1 + kk), *(const float4*)(ap1 + kk + 4));
        bf16x8 b  = pack8(*(const float4*)(bp  + kk), *(const float4*)(bp  + kk + 4));
        acc0 = __builtin_amdgcn_mfma_f32_16x16x32_bf16(a0, b, acc0, 0, 0, 0);
        acc1 = __builtin_amdgcn_mfma_f32_16x16x32_bf16(a1, b, acc1, 0, 0, 0);
    }
    float* dst = out_part + (size_t)blockIdx.y * (BSZ * DIM);
#pragma unroll
    for (int r = 0; r < 4; ++r) {
        int m = quad * 4 + r;
        dst[(size_t)m * DIM + n0 + c16]        = acc0[r];
        dst[(size_t)(m + 16) * DIM + n0 + c16] = acc1[r];
    }
}

extern "C" void kernel_launch(void* const* d_in, const int* in_sizes, int n_in,
                              void* d_out, int out_size, void* d_ws, size_t ws_size,
                              hipStream_t stream)
{
    const float* x   = (const float*)d_in[0];
    const float* wq  = (const float*)d_in[1];
    const float* wk  = (const float*)d_in[2];
    const float* wv  = (const float*)d_in[3];
    const float* wo  = (const float*)d_in[4];
    const float* ck0 = (const float*)d_in[5];
    const float* cv0 = (const float*)d_in[6];
    const float* ck1 = (const float*)d_in[7];
    const float* cv1 = (const float*)d_in[8];
    const float* fc  = (const float*)d_in[9];
    const float* fs  = (const float*)d_in[10];

    float* W = (float*)d_ws;
    float* gparts  = W;                                     // max(8*196608) floats, reused by out_gemm
    float* qkv     = gparts + (size_t)NSPLK * BSZ * QKVN;   // 196608
    float* part    = qkv + BSZ * QKVN;                      // 256*8*4*132
    float* attn    = part + (size_t)BSZ * NKV * MAXSPL * 4 * PSTRIDE; // 131072
    float* out     = (float*)d_out;

    qkv_gemm<<<dim3(QKVN / 64, NSPLK), 256, 0, stream>>>(x, wq, wk, wv, gparts);
    sum_splits<<<dim3(BSZ * QKVN / 1024), 256, 0, stream>>>((const float4*)gparts, (float4*)qkv, BSZ * QKVN / 4);
    attn_decode_split<<<dim3(1024 + 512), 256, 0, stream>>>(qkv, ck0, cv0, ck1, cv1, fc, fs, part);
    attn_reduce<<<dim3(BSZ * NKV), 64, 0, stream>>>(part, attn);
    out_gemm<<<dim3(DIM / 64, NSPLK), 256, 0, stream>>>(attn, wo, gparts);
    sum_splits<<<dim3(BSZ * DIM / 1024), 256, 0, stream>>>((const float4*)gparts, (float4*)out, BSZ * DIM / 4);
}